// Round 3
// baseline (324.907 us; speedup 1.0000x reference)
//
#include <hip/hip_runtime.h>

// TTLinearR: y = x @ W^T + b, W (4096x4096) = TT ranks [1,64,64,64,64,64,1].
// W = Amat(4096,64) @ Bmat(64,4096):
//   Amat = ((c0r(16,64)@c1r(64,1024)).reshape(256,64)@c2r(64,1024)).reshape(4096,64)
//   S3(1024,16) = c4r(1024,64)@c5r(64,16); Bmat(64,4096) = (c3r(1024,64)@S3view(64,256)) flat
// y = (x @ Bmat^T) @ Amat^T + b.  Traffic floor ~258 MB (~41 us).
//
// R6 (resubmit; R2 bench was an infra failure, no counters): de-fused pipeline.
// gemm1 does full-K per 16-token block -> t bf16 (1 MB, no K-split partials,
// no reduce kernel). gemm2 gets its own geometry: 128x256 tiles, 32x32x16
// MFMA whose C/D layout gives full 128B-line stores. Both run 2-3 blocks/CU.

#define TOK 8192
#define DIN 4096
#define DOUT 4096
#define RNK 64

// ---- gemm1 geometry ----
#define TB 16            // tokens per block
#define BK 256           // K per staged iter
#define NKI (DIN / BK)   // 16
#define XS 264           // LDS row stride in shorts (256 + 8 pad)
#define TSTR 66          // tred fp32 row stride

// ---- gemm2 geometry ----
#define G2M 128          // tokens per block
#define G2N 256          // out-cols per block
#define AS 72            // LDS row stride in shorts (64 + 8 pad)

typedef __bf16 bf16x8 __attribute__((ext_vector_type(8)));
typedef float f32x4 __attribute__((ext_vector_type(4)));
typedef float f32x16 __attribute__((ext_vector_type(16)));

__device__ __forceinline__ unsigned short f2bf(float f) {
  unsigned int u = __float_as_uint(f);
  u += 0x7FFFu + ((u >> 16) & 1u);  // RNE
  return (unsigned short)(u >> 16);
}

// ---- chain1: S1(16x1024) = c0(16,64)@c1(64,1024); S3(1024x16) = c4(1024,64)@c5(64,16)
__global__ void chain1(const float* __restrict__ c0, const float* __restrict__ c1,
                       const float* __restrict__ c4, const float* __restrict__ c5,
                       float* __restrict__ S1, float* __restrict__ S3) {
  int b = blockIdx.x;
  if (b < 64) {
    int idx = b * 256 + threadIdx.x;
    int m = idx >> 10, n = idx & 1023;
    const float* a = c0 + m * 64;
    float acc = 0.f;
#pragma unroll
    for (int k = 0; k < 64; ++k) acc += a[k] * c1[k * 1024 + n];
    S1[idx] = acc;
  } else {
    int idx = (b - 64) * 256 + threadIdx.x;
    int m = idx >> 4, n = idx & 15;
    const float* a = c4 + m * 64;
    float acc = 0.f;
#pragma unroll
    for (int k = 0; k < 64; ++k) acc += a[k] * c5[k * 16 + n];
    S3[idx] = acc;
  }
}

// ---- chain2: Abf = bf16(S1v(256,64)@c2(64,1024)) == Amat(4096,64) flat;
//              Bbf = bf16(c3(1024,64)@S3v(64,256)) == Bmat(64,4096) flat
__global__ void chain2(const float* __restrict__ S1, const float* __restrict__ c2,
                       const float* __restrict__ c3, const float* __restrict__ S3,
                       unsigned short* __restrict__ Abf, unsigned short* __restrict__ Bbf) {
  int b = blockIdx.x;
  if (b < 1024) {
    int idx = b * 256 + threadIdx.x;
    int m = idx >> 10, n = idx & 1023;
    const float* a = S1 + m * 64;
    float acc = 0.f;
#pragma unroll
    for (int k = 0; k < 64; ++k) acc += a[k] * c2[k * 1024 + n];
    Abf[idx] = f2bf(acc);
  } else {
    int idx = (b - 1024) * 256 + threadIdx.x;
    int m = idx >> 8, n = idx & 255;
    const float* a = c3 + m * 64;
    float acc = 0.f;
#pragma unroll
    for (int k = 0; k < 64; ++k) acc += a[k] * S3[k * 256 + n];
    Bbf[idx] = f2bf(acc);
  }
}

// ---- gemm1_t: t(8192,64) bf16 = x(8192,4096) @ Bmat(64,4096)^T ----
// 512 blocks x 16 tokens, full K per block. 8 waves: jrank = wv&3 (16-rank
// tile), khalf = wv>>2 (K-half of each BK tile). K-half partials merged via
// LDS at the end. LDS 42 KB -> 3 blocks/CU capacity.
__global__ __launch_bounds__(512)
void gemm1_t(const float* __restrict__ x, const unsigned short* __restrict__ Bbf,
             unsigned short* __restrict__ tb) {
  __shared__ __align__(16) unsigned short sm[(TB + 64) * XS];  // 42240 B
  unsigned short* xs = sm;            // TB x XS
  unsigned short* bs = sm + TB * XS;  // 64 x XS
  float* tred = (float*)sm;           // 16 x TSTR fp32 (overlaps xs; barrier-separated)

  const int tid = threadIdx.x;
  const int m0 = blockIdx.x * TB;
  const int lane = tid & 63, wv = tid >> 6;
  const int r = lane & 15, q = lane >> 4;
  const int khalf = wv >> 2, jrank = wv & 3;

  // staging maps: x 16x256 fp32 = 1024 float4 (2/thread); B 64x256 bf16 = 2048 uint4 (4/thread)
  int xr[2], xc[2], br[4], bc[4];
#pragma unroll
  for (int j = 0; j < 2; ++j) {
    int f = j * 512 + tid;
    xr[j] = f >> 6; xc[j] = f & 63;
  }
#pragma unroll
  for (int j = 0; j < 4; ++j) {
    int f = j * 512 + tid;
    br[j] = f >> 5; bc[j] = f & 31;
  }

  float4 px[2]; uint4 pb[4];
#pragma unroll
  for (int j = 0; j < 2; ++j)
    px[j] = *(const float4*)&x[(size_t)(m0 + xr[j]) * DIN + xc[j] * 4];
#pragma unroll
  for (int j = 0; j < 4; ++j)
    pb[j] = *(const uint4*)&Bbf[(size_t)br[j] * DIN + bc[j] * 8];

  f32x4 acc1 = (f32x4){0.f, 0.f, 0.f, 0.f};

#pragma unroll 1
  for (int ki = 0; ki < NKI; ++ki) {
    __syncthreads();  // previous tile's readers done
#pragma unroll
    for (int j = 0; j < 2; ++j) {
      ushort4 h = {f2bf(px[j].x), f2bf(px[j].y), f2bf(px[j].z), f2bf(px[j].w)};
      *(ushort4*)&xs[xr[j] * XS + xc[j] * 4] = h;
    }
#pragma unroll
    for (int j = 0; j < 4; ++j)
      *(uint4*)&bs[br[j] * XS + bc[j] * 8] = pb[j];
    if (ki + 1 < NKI) {  // issue next tile's loads early
      int k0n = (ki + 1) * BK;
#pragma unroll
      for (int j = 0; j < 2; ++j)
        px[j] = *(const float4*)&x[(size_t)(m0 + xr[j]) * DIN + k0n + xc[j] * 4];
#pragma unroll
      for (int j = 0; j < 4; ++j)
        pb[j] = *(const uint4*)&Bbf[(size_t)br[j] * DIN + k0n + bc[j] * 8];
    }
    __syncthreads();  // tile ready
#pragma unroll
    for (int s32 = 0; s32 < 4; ++s32) {
      const int koff = khalf * 128 + s32 * 32 + q * 8;
      bf16x8 afr = *(const bf16x8*)&xs[r * XS + koff];
      bf16x8 bfr = *(const bf16x8*)&bs[(jrank * 16 + r) * XS + koff];
      acc1 = __builtin_amdgcn_mfma_f32_16x16x32_bf16(afr, bfr, acc1, 0, 0, 0);
    }
  }

  // merge K-halves: waves 4..7 dump partials, waves 0..3 add + write t (bf16)
  // C/D: col = r (rank within 16-tile), row = q*4+g (token)
  __syncthreads();
  if (wv >= 4) {
#pragma unroll
    for (int g = 0; g < 4; ++g)
      tred[(q * 4 + g) * TSTR + jrank * 16 + r] = acc1[g];
  }
  __syncthreads();
  if (wv < 4) {
#pragma unroll
    for (int g = 0; g < 4; ++g) {
      float v = acc1[g] + tred[(q * 4 + g) * TSTR + jrank * 16 + r];
      tb[(size_t)(m0 + q * 4 + g) * RNK + jrank * 16 + r] = f2bf(v);
    }
  }
}

// ---- gemm2_y: y(8192,4096) = t(8192,64) @ Amat(4096,64)^T + b ----
// grid (16, 64): 128-token x 256-col tiles, K=64 staged once. 8 waves as
// 4 token-groups x 2 col-groups; per wave 32x128 via 4 x mfma_32x32x16 chains.
// 32x32 C/D layout: col = lane&31, row = (reg&3)+8*(reg>>2)+4*(lane>>5)
// -> every store covers two full 128B lines.
__global__ __launch_bounds__(512)
void gemm2_y(const unsigned short* __restrict__ tbf, const unsigned short* __restrict__ Abf,
             const float* __restrict__ bias, float* __restrict__ out) {
  __shared__ __align__(16) unsigned short sm[(G2M + G2N) * AS];  // 55296 B
  unsigned short* ts = sm;             // 128 x AS
  unsigned short* as_ = sm + G2M * AS; // 256 x AS

  const int tid = threadIdx.x;
  const int m0 = blockIdx.y * G2M, n0 = blockIdx.x * G2N;
  const int lane = tid & 63, wv = tid >> 6;
  const int l31 = lane & 31, hi = lane >> 5;
  const int mw = (wv >> 1) * 32, nw = (wv & 1) * 128;

  // stage t-tile (128x64, 2 uint4/thread) and Amat-tile (256x64, 4 uint4/thread)
#pragma unroll
  for (int j = 0; j < 2; ++j) {
    int f = j * 512 + tid;
    int row = f >> 3, c = f & 7;
    *(uint4*)&ts[row * AS + c * 8] = *(const uint4*)&tbf[(size_t)(m0 + row) * RNK + c * 8];
  }
#pragma unroll
  for (int j = 0; j < 4; ++j) {
    int f = j * 512 + tid;
    int row = f >> 3, c = f & 7;
    *(uint4*)&as_[row * AS + c * 8] = *(const uint4*)&Abf[(size_t)(n0 + row) * RNK + c * 8];
  }
  __syncthreads();

  f32x16 acc[4];
#pragma unroll
  for (int j = 0; j < 4; ++j)
#pragma unroll
    for (int e = 0; e < 16; ++e) acc[j][e] = 0.f;

#pragma unroll
  for (int ks = 0; ks < 4; ++ks) {
    bf16x8 a = *(const bf16x8*)&ts[(mw + l31) * AS + ks * 16 + hi * 8];
#pragma unroll
    for (int j = 0; j < 4; ++j) {
      bf16x8 b = *(const bf16x8*)&as_[(nw + j * 32 + l31) * AS + ks * 16 + hi * 8];
      acc[j] = __builtin_amdgcn_mfma_f32_32x32x16_bf16(a, b, acc[j], 0, 0, 0);
    }
  }

  float bb[4];
#pragma unroll
  for (int j = 0; j < 4; ++j) bb[j] = bias[n0 + nw + j * 32 + l31];

#pragma unroll
  for (int j = 0; j < 4; ++j) {
    const int col = n0 + nw + j * 32 + l31;
#pragma unroll
    for (int reg = 0; reg < 16; ++reg) {
      int rowt = (reg & 3) + 8 * (reg >> 2) + 4 * hi;
      out[(size_t)(m0 + mw + rowt) * DOUT + col] = acc[j][reg] + bb[j];
    }
  }
}

extern "C" void kernel_launch(void* const* d_in, const int* in_sizes, int n_in,
                              void* d_out, int out_size, void* d_ws, size_t ws_size,
                              hipStream_t stream) {
  const float* c0 = (const float*)d_in[0];
  const float* c1 = (const float*)d_in[1];
  const float* c2 = (const float*)d_in[2];
  const float* c3 = (const float*)d_in[3];
  const float* c4 = (const float*)d_in[4];
  const float* c5 = (const float*)d_in[5];
  const float* x  = (const float*)d_in[6];
  const float* bias = (const float*)d_in[7];
  float* out = (float*)d_out;

  char* ws = (char*)d_ws;
  float*          S1  = (float*)(ws);                               // 64 KB
  float*          S3  = (float*)(ws + (1u << 16));                  // 64 KB
  unsigned short* Abf = (unsigned short*)(ws + (2u << 16));         // 512 KB
  unsigned short* Bbf = (unsigned short*)(ws + (2u << 16) + (1u << 19));  // 512 KB
  unsigned short* tbf = (unsigned short*)(ws + (2u << 16) + (2u << 19));  // 1 MB

  chain1<<<128, 256, 0, stream>>>(c0, c1, c4, c5, S1, S3);
  chain2<<<2048, 256, 0, stream>>>(S1, c2, c3, S3, Abf, Bbf);
  gemm1_t<<<TOK / TB, 512, 0, stream>>>(x, Bbf, tbf);
  gemm2_y<<<dim3(DOUT / G2N, TOK / G2M), 512, 0, stream>>>(tbf, Abf, bias, out);
}

// Round 4
// 283.526 us; speedup vs baseline: 1.1460x; 1.1460x over previous
//
#include <hip/hip_runtime.h>

// TTLinearR: y = x @ W^T + b, W (4096x4096) = TT ranks [1,64,64,64,64,64,1].
// W = Amat(4096,64) @ Bmat(64,4096):
//   Amat = ((c0r(16,64)@c1r(64,1024)).reshape(256,64)@c2r(64,1024)).reshape(4096,64)
//   S3(1024,16) = c4r(1024,64)@c5r(64,16); Bmat(64,4096) = (c3r(1024,64)@S3view(64,256)) flat
// y = (x @ Bmat^T) @ Amat^T + b.  Traffic floor ~258 MB (~41 us).
//
// R7: barrier-free streaming GEMMs. R3's LDS-staged structure was latency-bound
// (113 us, 1.76 TB/s, 2 barriers + vmcnt(0) drain per K-step vs only 32 MFMA).
// The only data reuse here is x-row-across-rank-tiles (lives in the MFMA
// A-fragment registers) and Bmat/Amat/t across blocks (live in L2: 0.5-1 MB
// each). So: fragments load straight from HBM/L2 into registers, NO LDS GEMM
// staging, NO hot-loop barriers, 16 waves/CU. gemm1 splits K=4096 across the
// block's 8 waves and does one LDS reduction at the end -> bf16 t directly.
// gemm2 is pure register MFMA + dense stores.

#define TOK 8192
#define DIN 4096
#define DOUT 4096
#define RNK 64

typedef __bf16 bf16x8 __attribute__((ext_vector_type(8)));
typedef float f32x4 __attribute__((ext_vector_type(4)));
typedef float f32x16 __attribute__((ext_vector_type(16)));

__device__ __forceinline__ unsigned short f2bf(float f) {
  unsigned int u = __float_as_uint(f);
  u += 0x7FFFu + ((u >> 16) & 1u);  // RNE
  return (unsigned short)(u >> 16);
}

// ---- chain1: S1(16x1024) = c0(16,64)@c1(64,1024); S3(1024x16) = c4(1024,64)@c5(64,16)
__global__ void chain1(const float* __restrict__ c0, const float* __restrict__ c1,
                       const float* __restrict__ c4, const float* __restrict__ c5,
                       float* __restrict__ S1, float* __restrict__ S3) {
  int b = blockIdx.x;
  if (b < 64) {
    int idx = b * 256 + threadIdx.x;
    int m = idx >> 10, n = idx & 1023;
    const float* a = c0 + m * 64;
    float acc = 0.f;
#pragma unroll
    for (int k = 0; k < 64; ++k) acc += a[k] * c1[k * 1024 + n];
    S1[idx] = acc;
  } else {
    int idx = (b - 64) * 256 + threadIdx.x;
    int m = idx >> 4, n = idx & 15;
    const float* a = c4 + m * 64;
    float acc = 0.f;
#pragma unroll
    for (int k = 0; k < 64; ++k) acc += a[k] * c5[k * 16 + n];
    S3[idx] = acc;
  }
}

// ---- chain2: Abf = bf16(S1v(256,64)@c2(64,1024)) == Amat(4096,64) flat;
//              Bbf = bf16(c3(1024,64)@S3v(64,256)) == Bmat(64,4096) flat
__global__ void chain2(const float* __restrict__ S1, const float* __restrict__ c2,
                       const float* __restrict__ c3, const float* __restrict__ S3,
                       unsigned short* __restrict__ Abf, unsigned short* __restrict__ Bbf) {
  int b = blockIdx.x;
  if (b < 1024) {
    int idx = b * 256 + threadIdx.x;
    int m = idx >> 10, n = idx & 1023;
    const float* a = S1 + m * 64;
    float acc = 0.f;
#pragma unroll
    for (int k = 0; k < 64; ++k) acc += a[k] * c2[k * 1024 + n];
    Abf[idx] = f2bf(acc);
  } else {
    int idx = (b - 1024) * 256 + threadIdx.x;
    int m = idx >> 8, n = idx & 255;
    const float* a = c3 + m * 64;
    float acc = 0.f;
#pragma unroll
    for (int k = 0; k < 64; ++k) acc += a[k] * S3[k * 256 + n];
    Bbf[idx] = f2bf(acc);
  }
}

// ---- gemm1_s: t(8192,64) bf16 = x @ Bmat^T, streaming, barrier-free hot loop.
// 512 blocks x 512 thr (8 waves) = 16 waves/CU. Block owns 16 tokens, full K.
// Wave wv covers K-chunk [wv*512, wv*512+512): 16 K-steps of 32. Per step:
// A-frag = x rows (fp32->bf16 in regs, HBM), B-frags = 4 rank-tiles straight
// from L2 (Bbf is 512 KB, resident). One LDS reduction merges the 8 K-partials.
__global__ __launch_bounds__(512, 4)
void gemm1_s(const float* __restrict__ x, const unsigned short* __restrict__ Bbf,
             unsigned short* __restrict__ tb) {
  __shared__ float red[8 * 1024];  // 32 KB: per-wave 16x64 fp32 partials

  const int tid = threadIdx.x;
  const int m0 = blockIdx.x * 16;
  const int lane = tid & 63, wv = tid >> 6;
  const int r = lane & 15, q = lane >> 4;
  const size_t xrow = (size_t)(m0 + r) * DIN;
  const int k0w = wv * 512;

  f32x4 acc[4];
#pragma unroll
  for (int j = 0; j < 4; ++j) acc[j] = (f32x4){0.f, 0.f, 0.f, 0.f};

#pragma unroll
  for (int st = 0; st < 16; ++st) {
    const int k0 = k0w + st * 32 + q * 8;
    float4 xa = *(const float4*)&x[xrow + k0];
    float4 xb = *(const float4*)&x[xrow + k0 + 4];
    bf16x8 a;
    a[0] = (__bf16)xa.x; a[1] = (__bf16)xa.y; a[2] = (__bf16)xa.z; a[3] = (__bf16)xa.w;
    a[4] = (__bf16)xb.x; a[5] = (__bf16)xb.y; a[6] = (__bf16)xb.z; a[7] = (__bf16)xb.w;
#pragma unroll
    for (int j = 0; j < 4; ++j) {
      bf16x8 b = *(const bf16x8*)&Bbf[(size_t)(j * 16 + r) * DIN + k0];
      acc[j] = __builtin_amdgcn_mfma_f32_16x16x32_bf16(a, b, acc[j], 0, 0, 0);
    }
  }

  // C/D (16x16x32): col = r (rank-in-tile), row = q*4+g (token)
  float* myred = red + wv * 1024;
#pragma unroll
  for (int j = 0; j < 4; ++j)
#pragma unroll
    for (int g = 0; g < 4; ++g)
      myred[(q * 4 + g) * 64 + j * 16 + r] = acc[j][g];
  __syncthreads();

  // 512 threads sum 8 partials for 2 consecutive outputs each -> bf16 t
  const int o = tid * 2;
  float s0 = 0.f, s1 = 0.f;
#pragma unroll
  for (int w = 0; w < 8; ++w) {
    s0 += red[w * 1024 + o];
    s1 += red[w * 1024 + o + 1];
  }
  ushort2 h = {f2bf(s0), f2bf(s1)};
  *(ushort2*)&tb[(size_t)m0 * RNK + o] = h;
}

// ---- gemm2_s: y(8192,4096) = t(8192,64) @ Amat(4096,64)^T + b, LDS-free.
// grid (32, 32) x 256 thr (4 waves) = 16 waves/CU. Block: 128 cols x 256
// tokens. Wave wv: tokens mb + s*128 + wv*32 (s=0,1), all 128 cols in two
// 64-col passes (np) to cap VGPR <= 128. t/Amat frags straight from L2
// (1 MB + 0.5 MB resident); 32x32x16 MFMA; stores are 2x128B full segments.
__global__ __launch_bounds__(256, 4)
void gemm2_s(const unsigned short* __restrict__ tb, const unsigned short* __restrict__ Abf,
             const float* __restrict__ bias, float* __restrict__ out) {
  const int tid = threadIdx.x;
  const int lane = tid & 63, wv = tid >> 6;
  const int l31 = lane & 31, hi = lane >> 5;
  const int n0 = blockIdx.x * 128;
  const int mb = blockIdx.y * 256;

  float bb[4];
#pragma unroll
  for (int n = 0; n < 4; ++n) bb[n] = bias[n0 + n * 32 + l31];

#pragma unroll 1
  for (int s = 0; s < 2; ++s) {
    const int m0 = mb + s * 128 + wv * 32;
    // t A-frags (32x32x16: row = l31, k = ks*16 + hi*8 .. +7)
    bf16x8 ta[4];
#pragma unroll
    for (int ks = 0; ks < 4; ++ks)
      ta[ks] = *(const bf16x8*)&tb[(size_t)(m0 + l31) * RNK + ks * 16 + hi * 8];

#pragma unroll 1
    for (int np = 0; np < 2; ++np) {
      f32x16 acc[2];
#pragma unroll
      for (int j = 0; j < 2; ++j)
#pragma unroll
        for (int e = 0; e < 16; ++e) acc[j][e] = 0.f;

#pragma unroll
      for (int ks = 0; ks < 4; ++ks) {
#pragma unroll
        for (int j = 0; j < 2; ++j) {
          const int nrow = n0 + (np * 2 + j) * 32 + l31;
          bf16x8 b = *(const bf16x8*)&Abf[(size_t)nrow * RNK + ks * 16 + hi * 8];
          acc[j] = __builtin_amdgcn_mfma_f32_32x32x16_bf16(ta[ks], b, acc[j], 0, 0, 0);
        }
      }

      // 32x32 C/D: col = l31, row = (reg&3) + 8*(reg>>2) + 4*hi (verified R3)
#pragma unroll
      for (int j = 0; j < 2; ++j) {
        const int col = n0 + (np * 2 + j) * 32 + l31;
        const float bj = bb[np * 2 + j];
#pragma unroll
        for (int reg = 0; reg < 16; ++reg) {
          const int rowt = (reg & 3) + 8 * (reg >> 2) + 4 * hi;
          out[(size_t)(m0 + rowt) * DOUT + col] = acc[j][reg] + bj;
        }
      }
    }
  }
}

extern "C" void kernel_launch(void* const* d_in, const int* in_sizes, int n_in,
                              void* d_out, int out_size, void* d_ws, size_t ws_size,
                              hipStream_t stream) {
  const float* c0 = (const float*)d_in[0];
  const float* c1 = (const float*)d_in[1];
  const float* c2 = (const float*)d_in[2];
  const float* c3 = (const float*)d_in[3];
  const float* c4 = (const float*)d_in[4];
  const float* c5 = (const float*)d_in[5];
  const float* x  = (const float*)d_in[6];
  const float* bias = (const float*)d_in[7];
  float* out = (float*)d_out;

  char* ws = (char*)d_ws;
  float*          S1  = (float*)(ws);                               // 64 KB
  float*          S3  = (float*)(ws + (1u << 16));                  // 64 KB
  unsigned short* Abf = (unsigned short*)(ws + (2u << 16));         // 512 KB
  unsigned short* Bbf = (unsigned short*)(ws + (2u << 16) + (1u << 19));  // 512 KB
  unsigned short* tbf = (unsigned short*)(ws + (2u << 16) + (2u << 19));  // 1 MB

  chain1<<<128, 256, 0, stream>>>(c0, c1, c4, c5, S1, S3);
  chain2<<<2048, 256, 0, stream>>>(S1, c2, c3, S3, Abf, Bbf);
  gemm1_s<<<TOK / 16, 512, 0, stream>>>(x, Bbf, tbf);
  gemm2_s<<<dim3(DOUT / 128, TOK / 256), 256, 0, stream>>>(tbf, Abf, bias, out);
}

// Round 5
// 280.583 us; speedup vs baseline: 1.1580x; 1.0105x over previous
//
#include <hip/hip_runtime.h>

// TTLinearR: y = x @ W^T + b, W (4096x4096) = TT ranks [1,64,64,64,64,64,1].
// W = Amat(4096,64) @ Bmat(64,4096):
//   Amat = ((c0r(16,64)@c1r(64,1024)).reshape(256,64)@c2r(64,1024)).reshape(4096,64)
//   S3(1024,16) = c4r(1024,64)@c5r(64,16); Bmat(64,4096) = (c3r(1024,64)@S3view(64,256)) flat
// y = (x @ Bmat^T) @ Amat^T + b.  Traffic floor ~258 MB (~41 us).
//
// R8: delta-accounting across R0/R1/R3/R4 shows ~175-190 us of fixed harness
// fill overhead; controllable part is chains (~13) + GEMMs (93.3 in R4).
// R3's staged gemm2_y was already at its write floor (~21.5 us inferred) ->
// reverted here verbatim. gemm1 redone as a CONTROLLED depth-2 software
// pipeline (R4's fully-unrolled streaming loop had 96 hoisted loads -> VGPR
// pressure at the 128 cap + exposed HBM latency): #pragma unroll 1 loop,
// double-buffered x/B registers, prefetch st+2 after st's MFMAs, ~90 VGPR.

#define TOK 8192
#define DIN 4096
#define DOUT 4096
#define RNK 64

// ---- gemm2 geometry (R3 gemm2_y, measured at write floor) ----
#define G2M 128          // tokens per block
#define G2N 256          // out-cols per block
#define AS 72            // LDS row stride in shorts (64 + 8 pad)

typedef __bf16 bf16x8 __attribute__((ext_vector_type(8)));
typedef float f32x4 __attribute__((ext_vector_type(4)));
typedef float f32x16 __attribute__((ext_vector_type(16)));

__device__ __forceinline__ unsigned short f2bf(float f) {
  unsigned int u = __float_as_uint(f);
  u += 0x7FFFu + ((u >> 16) & 1u);  // RNE
  return (unsigned short)(u >> 16);
}

// ---- chain1: S1(16x1024) = c0(16,64)@c1(64,1024); S3(1024x16) = c4(1024,64)@c5(64,16)
__global__ void chain1(const float* __restrict__ c0, const float* __restrict__ c1,
                       const float* __restrict__ c4, const float* __restrict__ c5,
                       float* __restrict__ S1, float* __restrict__ S3) {
  int b = blockIdx.x;
  if (b < 64) {
    int idx = b * 256 + threadIdx.x;
    int m = idx >> 10, n = idx & 1023;
    const float* a = c0 + m * 64;
    float acc = 0.f;
#pragma unroll
    for (int k = 0; k < 64; ++k) acc += a[k] * c1[k * 1024 + n];
    S1[idx] = acc;
  } else {
    int idx = (b - 64) * 256 + threadIdx.x;
    int m = idx >> 4, n = idx & 15;
    const float* a = c4 + m * 64;
    float acc = 0.f;
#pragma unroll
    for (int k = 0; k < 64; ++k) acc += a[k] * c5[k * 16 + n];
    S3[idx] = acc;
  }
}

// ---- chain2: Abf = bf16(S1v(256,64)@c2(64,1024)) == Amat(4096,64) flat;
//              Bbf = bf16(c3(1024,64)@S3v(64,256)) == Bmat(64,4096) flat
__global__ void chain2(const float* __restrict__ S1, const float* __restrict__ c2,
                       const float* __restrict__ c3, const float* __restrict__ S3,
                       unsigned short* __restrict__ Abf, unsigned short* __restrict__ Bbf) {
  int b = blockIdx.x;
  if (b < 1024) {
    int idx = b * 256 + threadIdx.x;
    int m = idx >> 10, n = idx & 1023;
    const float* a = S1 + m * 64;
    float acc = 0.f;
#pragma unroll
    for (int k = 0; k < 64; ++k) acc += a[k] * c2[k * 1024 + n];
    Abf[idx] = f2bf(acc);
  } else {
    int idx = (b - 1024) * 256 + threadIdx.x;
    int m = idx >> 8, n = idx & 255;
    const float* a = c3 + m * 64;
    float acc = 0.f;
#pragma unroll
    for (int k = 0; k < 64; ++k) acc += a[k] * S3[k * 256 + n];
    Bbf[idx] = f2bf(acc);
  }
}

// ---- gemm1_p: t(8192,64) bf16 = x @ Bmat^T, barrier-free, depth-2 pipeline.
// 512 blocks x 512 thr (8 waves), 2 blocks/CU = 16 waves/CU. Block owns 16
// tokens; wave wv owns K-chunk [wv*512, +512) = 16 steps of 32. Per step:
// a-frag from x (fp32->bf16 in regs, HBM), 4 B-frags from L2 (Bbf 512 KB,
// resident). Double-buffered regs, prefetch st+2 issued after st's MFMAs.
// One LDS reduction merges the 8 K-partials -> bf16 t.
__global__ __launch_bounds__(512, 4)
void gemm1_p(const float* __restrict__ x, const unsigned short* __restrict__ Bbf,
             unsigned short* __restrict__ tb) {
  __shared__ float red[8 * 1024];  // 32 KB: per-wave 16x64 fp32 partials

  const int tid = threadIdx.x;
  const int m0 = blockIdx.x * 16;
  const int lane = tid & 63, wv = tid >> 6;
  const int r = lane & 15, q = lane >> 4;
  const float* xp = x + (size_t)(m0 + r) * DIN + wv * 512 + q * 8;
  const unsigned short* bp = Bbf + (size_t)r * DIN + wv * 512 + q * 8;

  f32x4 acc[4];
#pragma unroll
  for (int j = 0; j < 4; ++j) acc[j] = (f32x4){0.f, 0.f, 0.f, 0.f};

  // prologue: steps 0 (buf0) and 1 (buf1)
  float4 xa0 = *(const float4*)(xp);
  float4 xb0 = *(const float4*)(xp + 4);
  float4 xa1 = *(const float4*)(xp + 32);
  float4 xb1 = *(const float4*)(xp + 36);
  bf16x8 b0[4], b1[4];
#pragma unroll
  for (int j = 0; j < 4; ++j) {
    b0[j] = *(const bf16x8*)(bp + (size_t)j * 16 * DIN);
    b1[j] = *(const bf16x8*)(bp + (size_t)j * 16 * DIN + 32);
  }

#define G1_MFMA(XA, XB, BB)                                                      \
  {                                                                              \
    bf16x8 a;                                                                    \
    a[0] = (__bf16)XA.x; a[1] = (__bf16)XA.y;                                    \
    a[2] = (__bf16)XA.z; a[3] = (__bf16)XA.w;                                    \
    a[4] = (__bf16)XB.x; a[5] = (__bf16)XB.y;                                    \
    a[6] = (__bf16)XB.z; a[7] = (__bf16)XB.w;                                    \
    _Pragma("unroll")                                                            \
    for (int j = 0; j < 4; ++j)                                                  \
      acc[j] = __builtin_amdgcn_mfma_f32_16x16x32_bf16(a, BB[j], acc[j], 0, 0, 0); \
  }

#pragma unroll 1
  for (int st = 0; st < 14; st += 2) {
    G1_MFMA(xa0, xb0, b0);
    {  // prefetch step st+2 into buf0
      const float* xn = xp + (st + 2) * 32;
      const unsigned short* bn = bp + (st + 2) * 32;
      xa0 = *(const float4*)(xn);
      xb0 = *(const float4*)(xn + 4);
#pragma unroll
      for (int j = 0; j < 4; ++j) b0[j] = *(const bf16x8*)(bn + (size_t)j * 16 * DIN);
    }
    G1_MFMA(xa1, xb1, b1);
    {  // prefetch step st+3 into buf1
      const float* xn = xp + (st + 3) * 32;
      const unsigned short* bn = bp + (st + 3) * 32;
      xa1 = *(const float4*)(xn);
      xb1 = *(const float4*)(xn + 4);
#pragma unroll
      for (int j = 0; j < 4; ++j) b1[j] = *(const bf16x8*)(bn + (size_t)j * 16 * DIN);
    }
  }
  G1_MFMA(xa0, xb0, b0);  // step 14
  G1_MFMA(xa1, xb1, b1);  // step 15
#undef G1_MFMA

  // merge 8 K-partials. C/D: col = r (rank-in-tile), row = q*4+g (token)
  float* myred = red + wv * 1024;
#pragma unroll
  for (int j = 0; j < 4; ++j)
#pragma unroll
    for (int g = 0; g < 4; ++g)
      myred[(q * 4 + g) * 64 + j * 16 + r] = acc[j][g];
  __syncthreads();

  const int o = tid * 2;
  float s0 = 0.f, s1 = 0.f;
#pragma unroll
  for (int w = 0; w < 8; ++w) {
    s0 += red[w * 1024 + o];
    s1 += red[w * 1024 + o + 1];
  }
  ushort2 h = {f2bf(s0), f2bf(s1)};
  *(ushort2*)&tb[(size_t)m0 * RNK + o] = h;
}

// ---- gemm2_y: y(8192,4096) = t(8192,64) @ Amat(4096,64)^T + b ----
// (R3 version, inferred ~21.5 us = write floor.) grid (16,64): 128-token x
// 256-col tiles, K=64 staged once. 8 waves as 4 token-groups x 2 col-groups;
// 32x32x16 MFMA; C/D: col = lane&31, row = (reg&3)+8*(reg>>2)+4*(lane>>5)
// -> every store covers two full 128B lines.
__global__ __launch_bounds__(512)
void gemm2_y(const unsigned short* __restrict__ tbf, const unsigned short* __restrict__ Abf,
             const float* __restrict__ bias, float* __restrict__ out) {
  __shared__ __align__(16) unsigned short sm[(G2M + G2N) * AS];  // 55296 B
  unsigned short* ts = sm;             // 128 x AS
  unsigned short* as_ = sm + G2M * AS; // 256 x AS

  const int tid = threadIdx.x;
  const int m0 = blockIdx.y * G2M, n0 = blockIdx.x * G2N;
  const int lane = tid & 63, wv = tid >> 6;
  const int l31 = lane & 31, hi = lane >> 5;
  const int mw = (wv >> 1) * 32, nw = (wv & 1) * 128;

  // stage t-tile (128x64, 2 uint4/thread) and Amat-tile (256x64, 4 uint4/thread)
#pragma unroll
  for (int j = 0; j < 2; ++j) {
    int f = j * 512 + tid;
    int row = f >> 3, c = f & 7;
    *(uint4*)&ts[row * AS + c * 8] = *(const uint4*)&tbf[(size_t)(m0 + row) * RNK + c * 8];
  }
#pragma unroll
  for (int j = 0; j < 4; ++j) {
    int f = j * 512 + tid;
    int row = f >> 3, c = f & 7;
    *(uint4*)&as_[row * AS + c * 8] = *(const uint4*)&Abf[(size_t)(n0 + row) * RNK + c * 8];
  }
  __syncthreads();

  f32x16 acc[4];
#pragma unroll
  for (int j = 0; j < 4; ++j)
#pragma unroll
    for (int e = 0; e < 16; ++e) acc[j][e] = 0.f;

#pragma unroll
  for (int ks = 0; ks < 4; ++ks) {
    bf16x8 a = *(const bf16x8*)&ts[(mw + l31) * AS + ks * 16 + hi * 8];
#pragma unroll
    for (int j = 0; j < 4; ++j) {
      bf16x8 b = *(const bf16x8*)&as_[(nw + j * 32 + l31) * AS + ks * 16 + hi * 8];
      acc[j] = __builtin_amdgcn_mfma_f32_32x32x16_bf16(a, b, acc[j], 0, 0, 0);
    }
  }

  float bb[4];
#pragma unroll
  for (int j = 0; j < 4; ++j) bb[j] = bias[n0 + nw + j * 32 + l31];

#pragma unroll
  for (int j = 0; j < 4; ++j) {
    const int col = n0 + nw + j * 32 + l31;
#pragma unroll
    for (int reg = 0; reg < 16; ++reg) {
      int rowt = (reg & 3) + 8 * (reg >> 2) + 4 * hi;
      out[(size_t)(m0 + mw + rowt) * DOUT + col] = acc[j][reg] + bb[j];
    }
  }
}

extern "C" void kernel_launch(void* const* d_in, const int* in_sizes, int n_in,
                              void* d_out, int out_size, void* d_ws, size_t ws_size,
                              hipStream_t stream) {
  const float* c0 = (const float*)d_in[0];
  const float* c1 = (const float*)d_in[1];
  const float* c2 = (const float*)d_in[2];
  const float* c3 = (const float*)d_in[3];
  const float* c4 = (const float*)d_in[4];
  const float* c5 = (const float*)d_in[5];
  const float* x  = (const float*)d_in[6];
  const float* bias = (const float*)d_in[7];
  float* out = (float*)d_out;

  char* ws = (char*)d_ws;
  float*          S1  = (float*)(ws);                               // 64 KB
  float*          S3  = (float*)(ws + (1u << 16));                  // 64 KB
  unsigned short* Abf = (unsigned short*)(ws + (2u << 16));         // 512 KB
  unsigned short* Bbf = (unsigned short*)(ws + (2u << 16) + (1u << 19));  // 512 KB
  unsigned short* tbf = (unsigned short*)(ws + (2u << 16) + (2u << 19));  // 1 MB

  chain1<<<128, 256, 0, stream>>>(c0, c1, c4, c5, S1, S3);
  chain2<<<2048, 256, 0, stream>>>(S1, c2, c3, S3, Abf, Bbf);
  gemm1_p<<<TOK / 16, 512, 0, stream>>>(x, Bbf, tbf);
  gemm2_y<<<dim3(DOUT / G2N, TOK / G2M), 512, 0, stream>>>(tbf, Abf, bias, out);
}